// Round 5
// baseline (345.797 us; speedup 1.0000x reference)
//
#include <hip/hip_runtime.h>
#include <hip/hip_bf16.h>
#include <math.h>

#define Bb 4
#define Nn 2048
#define DIMd 128
#define Kk 32
#define H1 530      // EDGE_IN*2
#define PW2 530     // P table width (i-part only)
#define MD 16
#define NDH 256
#define NDI 144
#define HSP 552     // Hs row stride (bf16): 1104B row, 16B-aligned, ~2-way bank

typedef float f32x2 __attribute__((ext_vector_type(2)));
typedef float f32x4 __attribute__((ext_vector_type(4)));
typedef short s16x8 __attribute__((ext_vector_type(8)));

__device__ __forceinline__ unsigned short f2bf(float f){
    union { float f; unsigned u; } v; v.f = f;
    unsigned r = v.u + 0x7FFFu + ((v.u >> 16) & 1u);
    return (unsigned short)(r >> 16);
}
__device__ __forceinline__ float bf2f(unsigned short u){
    union { unsigned u; float f; } v; v.u = ((unsigned)u) << 16;
    return v.f;
}
__device__ __forceinline__ float silu_f(float x){
    float e = __builtin_amdgcn_exp2f(x * -1.442695041f);
    return x * __builtin_amdgcn_rcpf(1.0f + e);
}
__device__ __forceinline__ f32x2 silu2(f32x2 x){
    float e0 = __builtin_amdgcn_exp2f(x[0] * -1.442695041f);
    float e1 = __builtin_amdgcn_exp2f(x[1] * -1.442695041f);
    f32x2 r;
    r[0] = x[0] * __builtin_amdgcn_rcpf(1.0f + e0);
    r[1] = x[1] * __builtin_amdgcn_rcpf(1.0f + e1);
    return r;
}
__device__ __forceinline__ unsigned cvt_pk_bf16(float a, float b){
    unsigned r;
    asm("v_cvt_pk_bf16_f32 %0, %1, %2" : "=v"(r) : "v"(a), "v"(b));
    return r;
}

// ---------------- Kernel A: exact top-K=32, one wave per node, zero barriers ------------------
__global__ __launch_bounds__(256) void topk_kernel(const float* __restrict__ coors,
        int* __restrict__ idx_ws, float* __restrict__ dv_ws){
    int tid = threadIdx.x;
    int w = tid >> 6, lane = tid & 63;
    int node = blockIdx.x * 4 + w;
    int b = node >> 11;
    const float* cbp = coors + (size_t)b * Nn * 3;
    float cx = coors[node*3+0], cy = coors[node*3+1], cz = coors[node*3+2];
    float d[32];
    #pragma unroll
    for (int t = 0; t < 32; t++){
        int j = t*64 + lane;
        float dx = cx - cbp[j*3+0], dy = cy - cbp[j*3+1], dz = cz - cbp[j*3+2];
        d[t] = dx*dx + dy*dy + dz*dz;
    }
    float md = d[0]; int mj = lane;
    #pragma unroll
    for (int t = 1; t < 32; t++){
        int jt = t*64 + lane;
        if (d[t] < md){ md = d[t]; mj = jt; }
    }
    for (int r = 0; r < Kk; r++){
        float bd = md; int bj = mj;
        #pragma unroll
        for (int off = 32; off; off >>= 1){
            float d2 = __shfl_xor(bd, off); int j2 = __shfl_xor(bj, off);
            if (d2 < bd || (d2 == bd && j2 < bj)){ bd = d2; bj = j2; }
        }
        if (lane == 0){
            idx_ws[node*Kk + r] = bj;
            dv_ws[node*Kk + r] = bd;
        }
        if (mj == bj){
            md = 3.4e38f; mj = 0x7fffffff;
            #pragma unroll
            for (int t = 0; t < 32; t++){
                int jt = t*64 + lane;
                if (jt == bj) d[t] = 3.4e38f;
                if (d[t] < md){ md = d[t]; mj = jt; }
            }
        }
    }
}

// ---------------- Kernel F: build all MFMA B-fragments (bf16, fragment-linear) ----------------
__global__ __launch_bounds__(256) void fragw_kernel(const float* __restrict__ eW1,
        const float* __restrict__ eW2,
        unsigned short* __restrict__ W1F, unsigned short* __restrict__ WPF,
        unsigned short* __restrict__ W2F){
    int i0 = blockIdx.x * 256 + threadIdx.x;
    int stride = gridDim.x * 256;
    for (int i = i0; i < 34*5*512; i += stride){
        int j = i & 7, lane = (i >> 3) & 63, t = i >> 9;
        int ks = t % 5, nt = t / 5;
        int cg = nt*16 + (lane & 15);
        int k = ks*32 + ((lane >> 4) << 3) + j;
        float v = 0.f;
        if (cg < H1){
            if (k < 128) v = eW1[(size_t)(128+k)*H1 + cg];
            else if (k < 137) v = eW1[(size_t)(256+(k-128))*H1 + cg];
        }
        W1F[i] = f2bf(v);
    }
    for (int i = i0; i < 34*4*512; i += stride){
        int j = i & 7, lane = (i >> 3) & 63, t = i >> 9;
        int ks = t & 3, nt = t >> 2;
        int cg = nt*16 + (lane & 15);
        int k = ks*32 + ((lane >> 4) << 3) + j;
        float v = (cg < H1) ? eW1[(size_t)k*H1 + cg] : 0.f;
        WPF[i] = f2bf(v);
    }
    for (int i = i0; i < 17*512; i += stride){
        int j = i & 7, lane = (i >> 3) & 63, s = i >> 9;
        int k = s*32 + ((lane >> 4) << 3) + j;
        int col = lane & 15;
        W2F[i] = (k < H1) ? f2bf(eW2[(size_t)k*MD + col]) : (unsigned short)0;
    }
}

// ---------------- Kernel B: P_i = feats @ eW1_i + eb1 via MFMA, zero LDS ---------------------
__global__ __launch_bounds__(256) void pmat_kernel(const float* __restrict__ feats,
        const unsigned short* __restrict__ WPF, const float* __restrict__ eb1,
        float* __restrict__ P){
    int tid = threadIdx.x;
    int wid = tid >> 6, lane = tid & 63;
    int node0 = blockIdx.x * 32;
    int kg = (lane >> 4) * 8;
    s16x8 af[2][4];
    #pragma unroll
    for (int m = 0; m < 2; m++){
        const float* fr = feats + (size_t)(node0 + m*16 + (lane & 15)) * DIMd;
        #pragma unroll
        for (int ks = 0; ks < 4; ks++){
            f32x4 lo = *(const f32x4*)(fr + ks*32 + kg);
            f32x4 hi = *(const f32x4*)(fr + ks*32 + kg + 4);
            union { s16x8 v; unsigned u[4]; } pk;
            pk.u[0] = cvt_pk_bf16(lo[0], lo[1]); pk.u[1] = cvt_pk_bf16(lo[2], lo[3]);
            pk.u[2] = cvt_pk_bf16(hi[0], hi[1]); pk.u[3] = cvt_pk_bf16(hi[2], hi[3]);
            af[m][ks] = pk.v;
        }
    }
    const s16x8* WPFv = (const s16x8*)WPF;
    for (int nt = wid; nt < 34; nt += 4){
        f32x4 acc0 = {0,0,0,0}, acc1 = {0,0,0,0};
        #pragma unroll
        for (int ks = 0; ks < 4; ks++){
            s16x8 bb = WPFv[(nt*4 + ks)*64 + lane];
            acc0 = __builtin_amdgcn_mfma_f32_16x16x32_bf16(af[0][ks], bb, acc0, 0, 0, 0);
            acc1 = __builtin_amdgcn_mfma_f32_16x16x32_bf16(af[1][ks], bb, acc1, 0, 0, 0);
        }
        int cg = nt*16 + (lane & 15);
        if (cg < H1){
            float b = eb1[cg];
            int r0 = (lane >> 4) * 4;
            #pragma unroll
            for (int r = 0; r < 4; r++){
                P[(size_t)(node0 + r0 + r)*PW2 + cg]      = acc0[r] + b;
                P[(size_t)(node0 + 16 + r0 + r)*PW2 + cg] = acc1[r] + b;
            }
        }
    }
}

// ---------------- Kernel C: half-node edge pipeline (16 neighbors), 8 blocks/CU ---------------
__global__ __launch_bounds__(256, 8) void edge_kernel(const float* __restrict__ coors,
        const float* __restrict__ feats, const float* __restrict__ eb2,
        const float* __restrict__ cW1, const float* __restrict__ cb1,
        const float* __restrict__ cW2, const float* __restrict__ cb2,
        const float* __restrict__ P, const unsigned short* __restrict__ W1F,
        const unsigned short* __restrict__ W2F,
        const int* __restrict__ idx_ws, const float* __restrict__ dv_ws,
        float* __restrict__ mi_part, float* __restrict__ co_part){
    __shared__ unsigned short Hs[16][HSP];                  // 17664 B
    __shared__ unsigned short Pi_bf[544];                   // 1088 B
    __shared__ __align__(16) unsigned short aenc[16][32];   // 1024 B; overlaid by m_s
    __shared__ int js[16];
    __shared__ float rels[16][3];
    __shared__ float cacc[4][3];
    float (*m_s)[MD] = (float (*)[MD])aenc;

    int bid = blockIdx.x;
    int node = bid >> 1, h = bid & 1;
    int b = node >> 11;
    int tid = threadIdx.x;
    int wid = tid >> 6, lane = tid & 63;

    // stage Pi (bf16) and enc/rels/js for this half's 16 neighbors
    const float* Pn = P + (size_t)node*PW2;
    Pi_bf[tid] = f2bf(Pn[tid]);                               // tid < 256 < 530
    { int c = tid + 256; Pi_bf[c] = (c < PW2) ? f2bf(Pn[c]) : (unsigned short)0; }
    if (tid < 32){ int c = 512 + tid; Pi_bf[c] = (c < PW2) ? f2bf(Pn[c]) : (unsigned short)0; }
    if (tid < 16){
        int j = idx_ws[node*Kk + h*16 + tid];
        float dv = dv_ws[node*Kk + h*16 + tid];
        js[tid] = j;
        unsigned short e[9];
        e[0] = f2bf(sinf(dv));        e[1] = f2bf(sinf(dv*0.5f));
        e[2] = f2bf(sinf(dv*0.25f));  e[3] = f2bf(sinf(dv*0.125f));
        e[4] = f2bf(cosf(dv));        e[5] = f2bf(cosf(dv*0.5f));
        e[6] = f2bf(cosf(dv*0.25f));  e[7] = f2bf(cosf(dv*0.125f));
        e[8] = f2bf(dv);
        #pragma unroll
        for (int q = 0; q < 9; q++) aenc[tid][q] = e[q];
        #pragma unroll
        for (int q = 9; q < 32; q++) aenc[tid][q] = 0;
        int jg = (b << 11) + j;
        rels[tid][0] = coors[node*3+0] - coors[jg*3+0];
        rels[tid][1] = coors[node*3+1] - coors[jg*3+1];
        rels[tid][2] = coors[node*3+2] - coors[jg*3+2];
    }
    __syncthreads();

    // A-fragments in registers: [feats_j | enc] for the 16 neighbor rows
    int kg = (lane >> 4) * 8;
    int row = lane & 15;
    s16x8 af[5];
    {
        int jgl = (b << 11) + js[row];
        const float* fr = feats + (size_t)jgl * DIMd;
        #pragma unroll
        for (int ks = 0; ks < 4; ks++){
            f32x4 lo = *(const f32x4*)(fr + ks*32 + kg);
            f32x4 hi = *(const f32x4*)(fr + ks*32 + kg + 4);
            union { s16x8 v; unsigned u[4]; } pk;
            pk.u[0] = cvt_pk_bf16(lo[0], lo[1]); pk.u[1] = cvt_pk_bf16(lo[2], lo[3]);
            pk.u[2] = cvt_pk_bf16(hi[0], hi[1]); pk.u[3] = cvt_pk_bf16(hi[2], hi[3]);
            af[ks] = pk.v;
        }
        af[4] = *(const s16x8*)(&aenc[row][kg]);
    }

    // GEMM1: H(16x530) = A(16x160) @ W1F(160x530); epilogue +Pi, silu, ->bf16 Hs
    const s16x8* W1Fv = (const s16x8*)W1F;
    for (int nt = wid; nt < 34; nt += 4){
        f32x4 acc = {0,0,0,0};
        #pragma unroll
        for (int ks = 0; ks < 5; ks++){
            s16x8 bb = W1Fv[(nt*5 + ks)*64 + lane];
            acc = __builtin_amdgcn_mfma_f32_16x16x32_bf16(af[ks], bb, acc, 0, 0, 0);
        }
        int cg = nt*16 + (lane & 15);
        bool valid = cg < H1;
        float pic = bf2f(Pi_bf[cg]);
        int r0 = (lane >> 4) * 4;
        #pragma unroll
        for (int r = 0; r < 4; r++)
            Hs[r0 + r][cg] = valid ? f2bf(silu_f(acc[r] + pic)) : (unsigned short)0;
    }
    __syncthreads();

    // GEMM2: m_raw = H(16x530+pad) @ eW2(530x16), wave 0
    if (wid == 0){
        f32x4 acc = {0.f,0.f,0.f,0.f};
        int ar = lane & 15;
        const s16x8* W2Fv = (const s16x8*)W2F;
        for (int s = 0; s < 17; s++){
            s16x8 a  = *(const s16x8*)(&Hs[ar][s*32 + kg]);
            s16x8 bb = W2Fv[s*64 + lane];
            acc = __builtin_amdgcn_mfma_f32_16x16x32_bf16(a, bb, acc, 0, 0, 0);
        }
        int col = lane & 15, r0 = (lane >> 4) * 4;
        #pragma unroll
        for (int r = 0; r < 4; r++) m_s[r0 + r][col] = acc[r];
    }
    __syncthreads();
    { int n = tid >> 4, f = tid & 15; m_s[n][f] = silu_f(m_s[n][f] + eb2[f]); }
    __syncthreads();
    if (tid < MD){
        float s = 0.f;
        #pragma unroll
        for (int n = 0; n < 16; n++) s += m_s[n][tid];
        mi_part[bid*MD + tid] = s;
    }
    // cw MLP (16->64->1): 4 edges/wave, 16 lanes/edge, 4 hidden units/lane (f32x4)
    int eid = wid*4 + (lane >> 4);
    int u4 = (lane & 15) * 4;
    f32x4 acc4 = *(const f32x4*)(cb1 + u4);
    #pragma unroll
    for (int f = 0; f < MD; f++){
        float mv = m_s[eid][f];
        f32x4 w4 = *(const f32x4*)(cW1 + f*64 + u4);
        acc4 += (f32x4){mv,mv,mv,mv} * w4;
    }
    f32x4 c24 = *(const f32x4*)(cW2 + u4);
    float p = silu_f(acc4[0])*c24[0] + silu_f(acc4[1])*c24[1]
            + silu_f(acc4[2])*c24[2] + silu_f(acc4[3])*c24[3];
    #pragma unroll
    for (int off = 1; off < 16; off <<= 1) p += __shfl_xor(p, off);
    float cw = p + cb2[0];
    bool owner = (lane & 15) == 0;
    float vx = owner ? cw * rels[eid][0] : 0.f;
    float vy = owner ? cw * rels[eid][1] : 0.f;
    float vz = owner ? cw * rels[eid][2] : 0.f;
    vx += __shfl_xor(vx, 16); vx += __shfl_xor(vx, 32);
    vy += __shfl_xor(vy, 16); vy += __shfl_xor(vy, 32);
    vz += __shfl_xor(vz, 16); vz += __shfl_xor(vz, 32);
    if (lane == 0){ cacc[wid][0] = vx; cacc[wid][1] = vy; cacc[wid][2] = vz; }
    __syncthreads();
    if (tid == 0){
        co_part[bid*3+0] = cacc[0][0]+cacc[1][0]+cacc[2][0]+cacc[3][0];
        co_part[bid*3+1] = cacc[0][1]+cacc[1][1]+cacc[2][1]+cacc[3][1];
        co_part[bid*3+2] = cacc[0][2]+cacc[1][2]+cacc[2][2]+cacc[3][2];
    }
}

// ---------------- Kernel E: combine coors halves + residual ----------------------------------
__global__ __launch_bounds__(256) void combine_kernel(const float* __restrict__ coors,
        const float* __restrict__ co_part, float* __restrict__ coors_out){
    int i = blockIdx.x * 256 + threadIdx.x;
    if (i >= Bb*Nn*3) return;
    int n = i / 3, c = i - n*3;
    coors_out[i] = co_part[(n*2)*3 + c] + co_part[(n*2+1)*3 + c] + coors[i];
}

// ---------------- Kernel D: node MLP with residual, packed-f32 -------------------------------
__global__ __launch_bounds__(256) void node_kernel(const float* __restrict__ feats,
        const float* __restrict__ mi_part,
        const float* __restrict__ nW1, const float* __restrict__ nb1,
        const float* __restrict__ nW2, const float* __restrict__ nb2,
        float* __restrict__ out){
    __shared__ float insT[NDI][12];
    __shared__ float hsdT[NDH][12];
    int tid = threadIdx.x;
    int node0 = blockIdx.x * 8;
    for (int t = tid; t < 8*DIMd; t += 256){
        int m = t >> 7, k = t & 127;
        insT[k][m] = feats[(size_t)node0*DIMd + t];
    }
    if (tid < 8*MD){
        int m = tid >> 4, f = tid & 15;
        insT[DIMd + f][m] = mi_part[(size_t)(node0+m)*32 + f]
                          + mi_part[(size_t)(node0+m)*32 + 16 + f];
    }
    __syncthreads();
    float bias = nb1[tid];
    f32x2 acc[4];
    #pragma unroll
    for (int p = 0; p < 4; p++) acc[p] = (f32x2){bias, bias};
    for (int k = 0; k < NDI; k++){
        float wv = nW1[(size_t)k*NDH + tid];
        f32x2 w2 = {wv, wv};
        acc[0] += *(const f32x2*)&insT[k][0] * w2;
        acc[1] += *(const f32x2*)&insT[k][2] * w2;
        acc[2] += *(const f32x2*)&insT[k][4] * w2;
        acc[3] += *(const f32x2*)&insT[k][6] * w2;
    }
    #pragma unroll
    for (int p = 0; p < 4; p++) *(f32x2*)&hsdT[tid][2*p] = silu2(acc[p]);
    __syncthreads();
    int c = tid & 127, half = tid >> 7;
    float b2 = nb2[c];
    f32x2 a0 = {b2, b2}, a1 = {b2, b2};
    for (int k = 0; k < NDH; k++){
        float wv = nW2[(size_t)k*DIMd + c];
        f32x2 w2 = {wv, wv};
        a0 += *(const f32x2*)&hsdT[k][half*4]     * w2;
        a1 += *(const f32x2*)&hsdT[k][half*4 + 2] * w2;
    }
    #pragma unroll
    for (int q = 0; q < 4; q++){
        int m = half*4 + q;
        float v = (q < 2) ? a0[q & 1] : a1[q & 1];
        out[(size_t)(node0+m)*DIMd + c] = v + feats[(size_t)(node0+m)*DIMd + c];
    }
}

extern "C" void kernel_launch(void* const* d_in, const int* in_sizes, int n_in,
                              void* d_out, int out_size, void* d_ws, size_t ws_size,
                              hipStream_t stream){
    const float* feats = (const float*)d_in[0];
    const float* coors = (const float*)d_in[1];
    const float* eW1 = (const float*)d_in[2];
    const float* eb1 = (const float*)d_in[3];
    const float* eW2 = (const float*)d_in[4];
    const float* eb2 = (const float*)d_in[5];
    const float* cW1 = (const float*)d_in[6];
    const float* cb1 = (const float*)d_in[7];
    const float* cW2 = (const float*)d_in[8];
    const float* cb2 = (const float*)d_in[9];
    const float* nW1 = (const float*)d_in[10];
    const float* nb1 = (const float*)d_in[11];
    const float* nW2 = (const float*)d_in[12];
    const float* nb2 = (const float*)d_in[13];
    float* out = (float*)d_out;                        // node_out: 4*2048*128
    float* coors_out = out + (size_t)Bb*Nn*DIMd;       // coors_out: 4*2048*3

    char* ws = (char*)d_ws;
    size_t off = 0;
    int*   idx_ws = (int*)(ws + off);   off += (1u<<20);          // 1 MB
    float* dv_ws  = (float*)(ws + off); off += (1u<<20);          // 1 MB
    float* Pd     = (float*)(ws + off); off += 17367040u;         // 8192*530*4
    float* mi_part= (float*)(ws + off); off += (1u<<20);          // 16384*16*4
    float* co_part= (float*)(ws + off); off += 196608u;           // 16384*3*4
    unsigned short* W1F = (unsigned short*)(ws + off); off += 174080u;  // 34*5*512*2
    unsigned short* WPF = (unsigned short*)(ws + off); off += 139264u;  // 34*4*512*2
    unsigned short* W2F = (unsigned short*)(ws + off); off += 17408u;   // 17*512*2

    fragw_kernel<<<256, 256, 0, stream>>>(eW1, eW2, W1F, WPF, W2F);
    pmat_kernel<<<Bb*Nn/32, 256, 0, stream>>>(feats, WPF, eb1, Pd);
    topk_kernel<<<Bb*Nn/4, 256, 0, stream>>>(coors, idx_ws, dv_ws);
    edge_kernel<<<Bb*Nn*2, 256, 0, stream>>>(coors, feats, eb2, cW1, cb1, cW2, cb2,
                                             Pd, W1F, W2F, idx_ws, dv_ws, mi_part, co_part);
    combine_kernel<<<(Bb*Nn*3 + 255)/256, 256, 0, stream>>>(coors, co_part, coors_out);
    node_kernel<<<Bb*Nn/8, 256, 0, stream>>>(feats, mi_part, nW1, nb1, nW2, nb2, out);
}

// Round 7
// 304.875 us; speedup vs baseline: 1.1342x; 1.1342x over previous
//
#include <hip/hip_runtime.h>
#include <hip/hip_bf16.h>
#include <math.h>

#define Bb 4
#define Nn 2048
#define DIMd 128
#define Kk 32
#define H1 530      // EDGE_IN*2
#define PW2 530     // P table width (i-part only)
#define MD 16
#define NDH 256
#define NDI 144

typedef float f32x2 __attribute__((ext_vector_type(2)));
typedef float f32x4 __attribute__((ext_vector_type(4)));
typedef short s16x4 __attribute__((ext_vector_type(4)));
typedef short s16x8 __attribute__((ext_vector_type(8)));

__device__ __forceinline__ unsigned short f2bf(float f){
    union { float f; unsigned u; } v; v.f = f;
    unsigned r = v.u + 0x7FFFu + ((v.u >> 16) & 1u);
    return (unsigned short)(r >> 16);
}
__device__ __forceinline__ float silu_f(float x){
    float e = __builtin_amdgcn_exp2f(x * -1.442695041f);
    return x * __builtin_amdgcn_rcpf(1.0f + e);
}
__device__ __forceinline__ f32x2 silu2(f32x2 x){
    float e0 = __builtin_amdgcn_exp2f(x[0] * -1.442695041f);
    float e1 = __builtin_amdgcn_exp2f(x[1] * -1.442695041f);
    f32x2 r;
    r[0] = x[0] * __builtin_amdgcn_rcpf(1.0f + e0);
    r[1] = x[1] * __builtin_amdgcn_rcpf(1.0f + e1);
    return r;
}
__device__ __forceinline__ unsigned cvt_pk_bf16(float a, float b){
    unsigned r;
    asm("v_cvt_pk_bf16_f32 %0, %1, %2" : "=v"(r) : "v"(a), "v"(b));
    return r;
}

// ---------------- Kernel A: exact top-K=32, one wave per node, zero barriers ------------------
__global__ __launch_bounds__(256) void topk_kernel(const float* __restrict__ coors,
        int* __restrict__ idx_ws, float* __restrict__ dv_ws){
    int tid = threadIdx.x;
    int w = tid >> 6, lane = tid & 63;
    int node = blockIdx.x * 4 + w;
    int b = node >> 11;
    const float* cbp = coors + (size_t)b * Nn * 3;
    float cx = coors[node*3+0], cy = coors[node*3+1], cz = coors[node*3+2];
    float d[32];
    #pragma unroll
    for (int t = 0; t < 32; t++){
        int j = t*64 + lane;
        float dx = cx - cbp[j*3+0], dy = cy - cbp[j*3+1], dz = cz - cbp[j*3+2];
        d[t] = dx*dx + dy*dy + dz*dz;
    }
    float md = d[0]; int mj = lane;
    #pragma unroll
    for (int t = 1; t < 32; t++){
        int jt = t*64 + lane;
        if (d[t] < md){ md = d[t]; mj = jt; }
    }
    for (int r = 0; r < Kk; r++){
        float bd = md; int bj = mj;
        #pragma unroll
        for (int off = 32; off; off >>= 1){
            float d2 = __shfl_xor(bd, off); int j2 = __shfl_xor(bj, off);
            if (d2 < bd || (d2 == bd && j2 < bj)){ bd = d2; bj = j2; }
        }
        if (lane == 0){
            idx_ws[node*Kk + r] = bj;
            dv_ws[node*Kk + r] = bd;
        }
        if (mj == bj){
            md = 3.4e38f; mj = 0x7fffffff;
            #pragma unroll
            for (int t = 0; t < 32; t++){
                int jt = t*64 + lane;
                if (jt == bj) d[t] = 3.4e38f;
                if (d[t] < md){ md = d[t]; mj = jt; }
            }
        }
    }
}

// ---------------- Kernel F: build all MFMA B-fragments (bf16, fragment-linear) ----------------
__global__ __launch_bounds__(256) void fragw_kernel(const float* __restrict__ eW1,
        const float* __restrict__ eW2,
        unsigned short* __restrict__ W1F, unsigned short* __restrict__ WPF,
        unsigned short* __restrict__ W2F2){
    int i0 = blockIdx.x * 256 + threadIdx.x;
    int stride = gridDim.x * 256;
    for (int i = i0; i < 34*5*512; i += stride){
        int j = i & 7, lane = (i >> 3) & 63, t = i >> 9;
        int ks = t % 5, nt = t / 5;
        int cg = nt*16 + (lane & 15);
        int k = ks*32 + ((lane >> 4) << 3) + j;
        float v = 0.f;
        if (cg < H1){
            if (k < 128) v = eW1[(size_t)(128+k)*H1 + cg];
            else if (k < 137) v = eW1[(size_t)(256+(k-128))*H1 + cg];
        }
        W1F[i] = f2bf(v);
    }
    for (int i = i0; i < 34*4*512; i += stride){
        int j = i & 7, lane = (i >> 3) & 63, t = i >> 9;
        int ks = t & 3, nt = t >> 2;
        int cg = nt*16 + (lane & 15);
        int k = ks*32 + ((lane >> 4) << 3) + j;
        float v = (cg < H1) ? eW1[(size_t)k*H1 + cg] : 0.f;
        WPF[i] = f2bf(v);
    }
    for (int i = i0; i < 34*512; i += stride){
        int j = i & 7, lane = (i >> 3) & 63, nt = i >> 9;
        int kl = ((lane >> 4) << 3) + j;       // 0..31, valid < 16
        int col = lane & 15;
        int row = nt*16 + kl;
        float v = (kl < 16 && row < H1) ? eW2[(size_t)row*MD + col] : 0.f;
        W2F2[i] = f2bf(v);
    }
}

// ---------------- Kernel B: P_i = feats @ eW1_i + eb1 via MFMA, zero LDS ---------------------
__global__ __launch_bounds__(256) void pmat_kernel(const float* __restrict__ feats,
        const unsigned short* __restrict__ WPF, const float* __restrict__ eb1,
        float* __restrict__ P){
    int tid = threadIdx.x;
    int wid = tid >> 6, lane = tid & 63;
    int node0 = blockIdx.x * 32;
    int kg = (lane >> 4) * 8;
    s16x8 af[2][4];
    #pragma unroll
    for (int m = 0; m < 2; m++){
        const float* fr = feats + (size_t)(node0 + m*16 + (lane & 15)) * DIMd;
        #pragma unroll
        for (int ks = 0; ks < 4; ks++){
            f32x4 lo = *(const f32x4*)(fr + ks*32 + kg);
            f32x4 hi = *(const f32x4*)(fr + ks*32 + kg + 4);
            union { s16x8 v; unsigned u[4]; } pk;
            pk.u[0] = cvt_pk_bf16(lo[0], lo[1]); pk.u[1] = cvt_pk_bf16(lo[2], lo[3]);
            pk.u[2] = cvt_pk_bf16(hi[0], hi[1]); pk.u[3] = cvt_pk_bf16(hi[2], hi[3]);
            af[m][ks] = pk.v;
        }
    }
    const s16x8* WPFv = (const s16x8*)WPF;
    for (int nt = wid; nt < 34; nt += 4){
        f32x4 acc0 = {0,0,0,0}, acc1 = {0,0,0,0};
        #pragma unroll
        for (int ks = 0; ks < 4; ks++){
            s16x8 bb = WPFv[(nt*4 + ks)*64 + lane];
            acc0 = __builtin_amdgcn_mfma_f32_16x16x32_bf16(af[0][ks], bb, acc0, 0, 0, 0);
            acc1 = __builtin_amdgcn_mfma_f32_16x16x32_bf16(af[1][ks], bb, acc1, 0, 0, 0);
        }
        int cg = nt*16 + (lane & 15);
        if (cg < H1){
            float b = eb1[cg];
            int r0 = (lane >> 4) * 4;
            #pragma unroll
            for (int r = 0; r < 4; r++){
                P[(size_t)(node0 + r0 + r)*PW2 + cg]      = acc0[r] + b;
                P[(size_t)(node0 + 16 + r0 + r)*PW2 + cg] = acc1[r] + b;
            }
        }
    }
}

// ---------------- Kernel C: per-node edge pipeline, GEMM2 fused into GEMM1 epilogue -----------
#define TS 24   // T row stride (bf16): 48B, 16B-aligned, ~2-way bank on b128 reads
__global__ __launch_bounds__(256, 5) void edge_kernel(const float* __restrict__ coors,
        const float* __restrict__ feats, const float* __restrict__ eb2,
        const float* __restrict__ cW1, const float* __restrict__ cb1,
        const float* __restrict__ cW2, const float* __restrict__ cb2,
        const float* __restrict__ P, const unsigned short* __restrict__ W1F,
        const unsigned short* __restrict__ W2F2,
        const int* __restrict__ idx_ws, const float* __restrict__ dv_ws,
        float* __restrict__ mi_ws, float* __restrict__ coors_out){
    __shared__ float Pi_lds[544];                           // 2176 B (530 real, pad 0)
    __shared__ __align__(16) unsigned short aenc[Kk][32];   // 2048 B
    __shared__ int js[Kk];
    __shared__ float rels[Kk][3];
    __shared__ unsigned short T[4][16][TS];                 // 6144 B per-wave transpose bounce
    __shared__ float m_red[4][Kk][MD];                      // 8192 B partial m per wave
    __shared__ float cacc[4][3];

    int node = blockIdx.x; int tid = threadIdx.x;
    int b = node >> 11;
    int wid = tid >> 6, lane = tid & 63;

    // zero T pad cols 16..TS-1 (lanes with kg>=16 read these; their B rows are 0 so any
    // FINITE value is correct — must not read uninitialized LDS: NaN*0=NaN in MFMA)
    for (int t = tid; t < 4*16*(TS-16); t += 256){
        int w = t / (16*(TS-16)), rem = t % (16*(TS-16));
        T[w][rem / (TS-16)][16 + rem % (TS-16)] = 0;
    }
    // stage Pi (fp32) and enc/rels/js
    const float* Pn = P + (size_t)node*PW2;
    Pi_lds[tid]       = Pn[tid];
    { int c = tid + 256; Pi_lds[c] = (c < PW2) ? Pn[c] : 0.f; }
    if (tid < 32){ int c = 512 + tid; Pi_lds[c] = (c < PW2) ? Pn[c] : 0.f; }
    if (tid < Kk){
        int j = idx_ws[node*Kk + tid];
        float dv = dv_ws[node*Kk + tid];
        js[tid] = j;
        unsigned short e[9];
        e[0] = f2bf(sinf(dv));        e[1] = f2bf(sinf(dv*0.5f));
        e[2] = f2bf(sinf(dv*0.25f));  e[3] = f2bf(sinf(dv*0.125f));
        e[4] = f2bf(cosf(dv));        e[5] = f2bf(cosf(dv*0.5f));
        e[6] = f2bf(cosf(dv*0.25f));  e[7] = f2bf(cosf(dv*0.125f));
        e[8] = f2bf(dv);
        #pragma unroll
        for (int q = 0; q < 9; q++) aenc[tid][q] = e[q];
        #pragma unroll
        for (int q = 9; q < 32; q++) aenc[tid][q] = 0;
        int jg = (b << 11) + j;
        rels[tid][0] = coors[node*3+0] - coors[jg*3+0];
        rels[tid][1] = coors[node*3+1] - coors[jg*3+1];
        rels[tid][2] = coors[node*3+2] - coors[jg*3+2];
    }
    __syncthreads();

    // A-fragments in registers: [feats_j | enc] for this block's 32 neighbors (M=32)
    int kg = (lane >> 4) * 8;
    int kga = (kg >= 16) ? 16 : kg;   // clamp GEMM2 A-frag reads into the zeroed pad
    s16x8 af[2][5];
    #pragma unroll
    for (int m = 0; m < 2; m++){
        int row = m*16 + (lane & 15);
        int jgl = (b << 11) + js[row];
        const float* fr = feats + (size_t)jgl * DIMd;
        #pragma unroll
        for (int ks = 0; ks < 4; ks++){
            f32x4 lo = *(const f32x4*)(fr + ks*32 + kg);
            f32x4 hi = *(const f32x4*)(fr + ks*32 + kg + 4);
            union { s16x8 v; unsigned u[4]; } pk;
            pk.u[0] = cvt_pk_bf16(lo[0], lo[1]); pk.u[1] = cvt_pk_bf16(lo[2], lo[3]);
            pk.u[2] = cvt_pk_bf16(hi[0], hi[1]); pk.u[3] = cvt_pk_bf16(hi[2], hi[3]);
            af[m][ks] = pk.v;
        }
        af[m][4] = *(const s16x8*)(&aenc[row][kg]);
    }

    // Fused GEMM1+silu+GEMM2: per nt-tile of 16 H-cols, contract into per-wave partial m
    const s16x8* W1Fv  = (const s16x8*)W1F;
    const s16x8* W2F2v = (const s16x8*)W2F2;
    f32x4 macc0 = {0,0,0,0}, macc1 = {0,0,0,0};
    int col = lane & 15, r0 = (lane >> 4) * 4;
    for (int nt = wid; nt < 34; nt += 4){
        f32x4 acc0 = {0,0,0,0}, acc1 = {0,0,0,0};
        #pragma unroll
        for (int ks = 0; ks < 5; ks++){
            s16x8 bb = W1Fv[(nt*5 + ks)*64 + lane];
            acc0 = __builtin_amdgcn_mfma_f32_16x16x32_bf16(af[0][ks], bb, acc0, 0, 0, 0);
            acc1 = __builtin_amdgcn_mfma_f32_16x16x32_bf16(af[1][ks], bb, acc1, 0, 0, 0);
        }
        int cg = nt*16 + col;
        bool valid = cg < H1;
        float pic = Pi_lds[cg];
        s16x8 w2b = W2F2v[nt*64 + lane];
        // m = 0: transpose-bounce h0 through T[wid], then MFMA into macc0
        #pragma unroll
        for (int r = 0; r < 4; r++)
            T[wid][r0 + r][col] = valid ? f2bf(silu_f(acc0[r] + pic)) : (unsigned short)0;
        {
            union { s16x8 v; s16x4 h[2]; } a2;
            a2.h[0] = *(const s16x4*)&T[wid][col][kga];
            a2.h[1] = *(const s16x4*)&T[wid][col][kga + 4];
            macc0 = __builtin_amdgcn_mfma_f32_16x16x32_bf16(a2.v, w2b, macc0, 0, 0, 0);
        }
        // m = 1
        #pragma unroll
        for (int r = 0; r < 4; r++)
            T[wid][r0 + r][col] = valid ? f2bf(silu_f(acc1[r] + pic)) : (unsigned short)0;
        {
            union { s16x8 v; s16x4 h[2]; } a2;
            a2.h[0] = *(const s16x4*)&T[wid][col][kga];
            a2.h[1] = *(const s16x4*)&T[wid][col][kga + 4];
            macc1 = __builtin_amdgcn_mfma_f32_16x16x32_bf16(a2.v, w2b, macc1, 0, 0, 0);
        }
    }
    // write per-wave partial m; reduce across waves
    #pragma unroll
    for (int r = 0; r < 4; r++){
        m_red[wid][r0 + r][col]      = macc0[r];
        m_red[wid][16 + r0 + r][col] = macc1[r];
    }
    __syncthreads();
    #pragma unroll
    for (int t = tid; t < Kk*MD; t += 256){
        int n = t >> 4, f = t & 15;
        float s = m_red[0][n][f] + m_red[1][n][f] + m_red[2][n][f] + m_red[3][n][f];
        m_red[0][n][f] = silu_f(s + eb2[f]);
    }
    __syncthreads();
    if (tid < MD){
        float s = 0.f;
        #pragma unroll
        for (int n = 0; n < Kk; n++) s += m_red[0][n][tid];
        mi_ws[node*MD + tid] = s;
    }
    // cw MLP (16->64->1): 8 edges/wave, 16 lanes/edge, 4 hidden units/lane
    float vx = 0.f, vy = 0.f, vz = 0.f;
    int u4 = col * 4;
    f32x4 cb14 = *(const f32x4*)(cb1 + u4);
    f32x4 c24  = *(const f32x4*)(cW2 + u4);
    #pragma unroll
    for (int q = 0; q < 2; q++){
        int eid = wid*8 + (lane >> 4)*2 + q;
        f32x4 acc4 = cb14;
        #pragma unroll
        for (int f = 0; f < MD; f++){
            float mv = m_red[0][eid][f];
            f32x4 w4 = *(const f32x4*)(cW1 + f*64 + u4);
            acc4 += (f32x4){mv,mv,mv,mv} * w4;
        }
        float p = silu_f(acc4[0])*c24[0] + silu_f(acc4[1])*c24[1]
                + silu_f(acc4[2])*c24[2] + silu_f(acc4[3])*c24[3];
        #pragma unroll
        for (int off = 1; off < 16; off <<= 1) p += __shfl_xor(p, off);
        float cw = p + cb2[0];
        if (col == 0){
            vx += cw * rels[eid][0];
            vy += cw * rels[eid][1];
            vz += cw * rels[eid][2];
        }
    }
    vx += __shfl_xor(vx, 16); vx += __shfl_xor(vx, 32);
    vy += __shfl_xor(vy, 16); vy += __shfl_xor(vy, 32);
    vz += __shfl_xor(vz, 16); vz += __shfl_xor(vz, 32);
    if (lane == 0){ cacc[wid][0] = vx; cacc[wid][1] = vy; cacc[wid][2] = vz; }
    __syncthreads();
    if (tid == 0){
        coors_out[node*3+0] = cacc[0][0]+cacc[1][0]+cacc[2][0]+cacc[3][0] + coors[node*3+0];
        coors_out[node*3+1] = cacc[0][1]+cacc[1][1]+cacc[2][1]+cacc[3][1] + coors[node*3+1];
        coors_out[node*3+2] = cacc[0][2]+cacc[1][2]+cacc[2][2]+cacc[3][2] + coors[node*3+2];
    }
}

// ---------------- Kernel D: node MLP with residual, packed-f32 -------------------------------
__global__ __launch_bounds__(256) void node_kernel(const float* __restrict__ feats,
        const float* __restrict__ mi_ws,
        const float* __restrict__ nW1, const float* __restrict__ nb1,
        const float* __restrict__ nW2, const float* __restrict__ nb2,
        float* __restrict__ out){
    __shared__ float insT[NDI][12];
    __shared__ float hsdT[NDH][12];
    int tid = threadIdx.x;
    int node0 = blockIdx.x * 8;
    for (int t = tid; t < 8*DIMd; t += 256){
        int m = t >> 7, k = t & 127;
        insT[k][m] = feats[(size_t)node0*DIMd + t];
    }
    if (tid < 8*MD) insT[DIMd + (tid & 15)][tid >> 4] = mi_ws[node0*MD + tid];
    __syncthreads();
    float bias = nb1[tid];
    f32x2 acc[4];
    #pragma unroll
    for (int p = 0; p < 4; p++) acc[p] = (f32x2){bias, bias};
    for (int k = 0; k < NDI; k++){
        float wv = nW1[(size_t)k*NDH + tid];
        f32x2 w2 = {wv, wv};
        acc[0] += *(const f32x2*)&insT[k][0] * w2;
        acc[1] += *(const f32x2*)&insT[k][2] * w2;
        acc[2] += *(const f32x2*)&insT[k][4] * w2;
        acc[3] += *(const f32x2*)&insT[k][6] * w2;
    }
    #pragma unroll
    for (int p = 0; p < 4; p++) *(f32x2*)&hsdT[tid][2*p] = silu2(acc[p]);
    __syncthreads();
    int c = tid & 127, half = tid >> 7;
    float b2 = nb2[c];
    f32x2 a0 = {b2, b2}, a1 = {b2, b2};
    for (int k = 0; k < NDH; k++){
        float wv = nW2[(size_t)k*DIMd + c];
        f32x2 w2 = {wv, wv};
        a0 += *(const f32x2*)&hsdT[k][half*4]     * w2;
        a1 += *(const f32x2*)&hsdT[k][half*4 + 2] * w2;
    }
    #pragma unroll
    for (int q = 0; q < 4; q++){
        int m = half*4 + q;
        float v = (q < 2) ? a0[q & 1] : a1[q & 1];
        out[(size_t)(node0+m)*DIMd + c] = v + feats[(size_t)(node0+m)*DIMd + c];
    }
}

extern "C" void kernel_launch(void* const* d_in, const int* in_sizes, int n_in,
                              void* d_out, int out_size, void* d_ws, size_t ws_size,
                              hipStream_t stream){
    const float* feats = (const float*)d_in[0];
    const float* coors = (const float*)d_in[1];
    const float* eW1 = (const float*)d_in[2];
    const float* eb1 = (const float*)d_in[3];
    const float* eW2 = (const float*)d_in[4];
    const float* eb2 = (const float*)d_in[5];
    const float* cW1 = (const float*)d_in[6];
    const float* cb1 = (const float*)d_in[7];
    const float* cW2 = (const float*)d_in[8];
    const float* cb2 = (const float*)d_in[9];
    const float* nW1 = (const float*)d_in[10];
    const float* nb1 = (const float*)d_in[11];
    const float* nW2 = (const float*)d_in[12];
    const float* nb2 = (const float*)d_in[13];
    float* out = (float*)d_out;                        // node_out: 4*2048*128
    float* coors_out = out + (size_t)Bb*Nn*DIMd;       // coors_out: 4*2048*3

    char* ws = (char*)d_ws;
    size_t off = 0;
    int*   idx_ws = (int*)(ws + off);   off += (1u<<20);          // 1 MB
    float* dv_ws  = (float*)(ws + off); off += (1u<<20);          // 1 MB
    float* Pd     = (float*)(ws + off); off += 17367040u;         // 8192*530*4
    float* mi_ws  = (float*)(ws + off); off += 524288u;           // 8192*16*4
    unsigned short* W1F  = (unsigned short*)(ws + off); off += 174080u;  // 34*5*512*2
    unsigned short* WPF  = (unsigned short*)(ws + off); off += 139264u;  // 34*4*512*2
    unsigned short* W2F2 = (unsigned short*)(ws + off); off += 34816u;   // 34*512*2

    fragw_kernel<<<256, 256, 0, stream>>>(eW1, eW2, W1F, WPF, W2F2);
    pmat_kernel<<<Bb*Nn/32, 256, 0, stream>>>(feats, WPF, eb1, Pd);
    topk_kernel<<<Bb*Nn/4, 256, 0, stream>>>(coors, idx_ws, dv_ws);
    edge_kernel<<<Bb*Nn, 256, 0, stream>>>(coors, feats, eb2, cW1, cb1, cW2, cb2,
                                           Pd, W1F, W2F2, idx_ws, dv_ws, mi_ws, coors_out);
    node_kernel<<<Bb*Nn/8, 256, 0, stream>>>(feats, mi_ws, nW1, nb1, nW2, nb2, out);
}